// Round 2
// baseline (314.080 us; speedup 1.0000x reference)
//
#include <hip/hip_runtime.h>
#include <hip/hip_bf16.h>

typedef __bf16 bf16;
typedef __bf16 bf16x8 __attribute__((ext_vector_type(8)));
typedef float  f32x4  __attribute__((ext_vector_type(4)));

#define MFMA16(A,B,C) __builtin_amdgcn_mfma_f32_16x16x32_bf16((A),(B),(C),0,0,0)

constexpr int NI    = 64;     // instances
constexpr int NN    = 128;    // N (embedding rows / output cols)
constexpr int E     = 256;    // embed dim
constexpr int HID   = 1024;   // hidden
constexpr int BATCH = 2048;
constexpr int BM    = 128;    // batch rows per block
constexpr int BH    = 64;     // hidden chunk
constexpr int W1P   = E  + 8; // LDS stride: 132 dwords = 4 mod 32 -> rows spread banks
constexpr int W2P   = BH + 8; // 36 dwords = 4 mod 32
constexpr int HP    = BH + 8;

// ---------------------------------------------------------------------------
// Per-instance transpose + fp32->bf16: in [NI][R][C] f32 -> out [NI][C][R] bf16
// ---------------------------------------------------------------------------
__global__ __launch_bounds__(256) void transpose_cvt(
    const float* __restrict__ in, bf16* __restrict__ out, int R, int C)
{
    __shared__ bf16 t[64][74];   // 74: dword stride 37 (odd) -> ~2-way max
    const int inst = blockIdx.z;
    const int r0 = blockIdx.y * 64, c0 = blockIdx.x * 64;
    const float* ip = in + ((size_t)inst * R + r0) * C + c0;
    #pragma unroll
    for (int it = 0; it < 4; ++it) {
        int idx = it * 256 + threadIdx.x;
        int r = idx >> 4, c4 = idx & 15;
        f32x4 v = *(const f32x4*)(ip + (size_t)r * C + c4 * 4);
        #pragma unroll
        for (int k = 0; k < 4; ++k) t[r][c4 * 4 + k] = (bf16)v[k];
    }
    __syncthreads();
    bf16* op = out + ((size_t)inst * C + c0) * R + r0;
    #pragma unroll
    for (int it = 0; it < 2; ++it) {
        int idx = it * 256 + threadIdx.x;
        int c = idx >> 3, r8 = idx & 7;
        bf16x8 tmp;
        #pragma unroll
        for (int k = 0; k < 8; ++k) tmp[k] = t[r8 * 8 + k][c];
        *(bf16x8*)(op + (size_t)c * R + r8 * 8) = tmp;
    }
}

__device__ __forceinline__ float fast_gelu(float x) {
    // tanh-form GELU: x * sigmoid(1.5957691*(x + 0.044715 x^3))
    float p = 1.5957691216f * __builtin_fmaf(0.044715f * x * x, x, x);
    return x * __builtin_amdgcn_rcpf(1.0f + __expf(-p));
}

// ---------------------------------------------------------------------------
// Fused MLP. Inputs fp32 (emb) / bf16 (pre-transposed weights); output fp32.
// PRET=true : W1 = W1T bf16 [NI][HID][E], W2 = W2T bf16 [NI][NN][HID]
// PRET=false: W1 = linear f32 [NI][E][HID], W2 = unemb f32 [NI][HID][NN]
// Block: 256 thr = 4 waves; one (instance, 128-row batch tile); 16 hidden chunks.
// ---------------------------------------------------------------------------
template <bool PRET>
__global__ __launch_bounds__(256, 2) void mlp3_fused(
    const int*   __restrict__ a,
    const float* __restrict__ embL,
    const float* __restrict__ embR,
    const void*  __restrict__ W1v,
    const void*  __restrict__ W2v,
    float* __restrict__ out)
{
    __shared__ __align__(16) bf16 sW1[BH][W1P];  // [h_local][e]   33792 B
    __shared__ __align__(16) bf16 sW2[NN][W2P];  // [n][h_local]    18432 B
    __shared__ __align__(16) bf16 sH [BM][HP];   // [row][h_local]  18432 B
    static_assert(sizeof(bf16) * (BH * W1P + NN * W2P + BM * HP) <= 80 * 1024, "2 blocks/CU");

    // XCD swizzle: consecutive blocks on one XCD share the instance -> weights L2-hot.
    const int blk   = blockIdx.x;
    const int xcd   = blk & 7;
    const int j     = blk >> 3;          // 0..127, round-robin position on this XCD
    const int inst  = xcd + 8 * (j >> 4);
    const int btile = j & 15;

    const int tid  = threadIdx.x;
    const int wave = tid >> 6;
    const int lane = tid & 63;
    const int m = lane & 15;             // MFMA row/col within 16-tile
    const int q = lane >> 4;             // quad

    // ---- build A fragments (this wave's 32 rows x 256 e) in registers ----
    bf16x8 aF[2][8];
    #pragma unroll
    for (int rt = 0; rt < 2; ++rt) {
        const int r  = btile * BM + wave * 32 + rt * 16 + m;
        const int i1 = a[2 * r + 0];
        const int i2 = a[2 * r + 1];
        const float* pl = embL + ((size_t)inst * NN + i1) * E;
        const float* pr = embR + ((size_t)inst * NN + i2) * E;
        #pragma unroll
        for (int ks = 0; ks < 8; ++ks) {
            const int e0 = ks * 32 + q * 8;
            f32x4 l0 = *(const f32x4*)(pl + e0);
            f32x4 l1 = *(const f32x4*)(pl + e0 + 4);
            f32x4 r0 = *(const f32x4*)(pr + e0);
            f32x4 r1 = *(const f32x4*)(pr + e0 + 4);
            bf16x8 s;
            #pragma unroll
            for (int k = 0; k < 4; ++k) {
                s[k]     = (bf16)(l0[k] + r0[k]);
                s[k + 4] = (bf16)(l1[k] + r1[k]);
            }
            aF[rt][ks] = s;
        }
    }

    f32x4 O[2][8];
    #pragma unroll
    for (int rt = 0; rt < 2; ++rt)
        #pragma unroll
        for (int ct = 0; ct < 8; ++ct)
            O[rt][ct] = (f32x4){0.f, 0.f, 0.f, 0.f};

    #pragma unroll 1
    for (int c = 0; c < HID / BH; ++c) {
        __syncthreads();  // prev chunk's LDS reads done before restage
        if (PRET) {
            const bf16* W1 = (const bf16*)W1v;  // [NI][HID][E]
            const bf16* W2 = (const bf16*)W2v;  // [NI][NN][HID]
            #pragma unroll
            for (int it = 0; it < 8; ++it) {
                const int idx = it * 256 + tid;
                const int hl = idx >> 5, e16 = idx & 31;
                *(bf16x8*)&sW1[hl][e16 * 8] =
                    *(const bf16x8*)(W1 + ((size_t)inst * HID + c * BH + hl) * E + e16 * 8);
            }
            #pragma unroll
            for (int it = 0; it < 4; ++it) {
                const int idx = it * 256 + tid;
                const int n = idx >> 3, h8 = idx & 7;
                *(bf16x8*)&sW2[n][h8 * 8] =
                    *(const bf16x8*)(W2 + ((size_t)inst * NN + n) * HID + c * BH + h8 * 8);
            }
        } else {
            const float* W1 = (const float*)W1v;  // [NI][E][HID]
            const float* W2 = (const float*)W2v;  // [NI][HID][NN]
            #pragma unroll
            for (int it = 0; it < 8; ++it) {
                const int idx = it * 256 + tid;
                const int e = idx >> 3, h8 = idx & 7;
                f32x4 v0 = *(const f32x4*)(W1 + ((size_t)inst * E + e) * HID + c * BH + h8 * 8);
                f32x4 v1 = *(const f32x4*)(W1 + ((size_t)inst * E + e) * HID + c * BH + h8 * 8 + 4);
                #pragma unroll
                for (int k = 0; k < 4; ++k) {
                    sW1[h8 * 8 + k][e]     = (bf16)v0[k];
                    sW1[h8 * 8 + k + 4][e] = (bf16)v1[k];
                }
            }
            #pragma unroll
            for (int it = 0; it < 4; ++it) {
                const int idx = it * 256 + tid;
                const int h = idx >> 4, n8 = idx & 15;
                f32x4 v0 = *(const f32x4*)(W2 + ((size_t)inst * HID + c * BH + h) * NN + n8 * 8);
                f32x4 v1 = *(const f32x4*)(W2 + ((size_t)inst * HID + c * BH + h) * NN + n8 * 8 + 4);
                #pragma unroll
                for (int k = 0; k < 4; ++k) {
                    sW2[n8 * 8 + k][h]     = (bf16)v0[k];
                    sW2[n8 * 8 + k + 4][h] = (bf16)v1[k];
                }
            }
        }
        __syncthreads();

        // ---- GEMM1: S(32x64 per wave) = A @ W1c ----
        f32x4 S[2][4];
        #pragma unroll
        for (int rt = 0; rt < 2; ++rt)
            #pragma unroll
            for (int ct = 0; ct < 4; ++ct) S[rt][ct] = (f32x4){0.f, 0.f, 0.f, 0.f};
        #pragma unroll
        for (int ks = 0; ks < 8; ++ks) {
            #pragma unroll
            for (int ct = 0; ct < 4; ++ct) {
                bf16x8 b = *(const bf16x8*)&sW1[ct * 16 + m][ks * 32 + q * 8];
                S[0][ct] = MFMA16(aF[0][ks], b, S[0][ct]);
                S[1][ct] = MFMA16(aF[1][ks], b, S[1][ct]);
            }
        }

        // ---- GELU, C/D-layout -> wave-private LDS rows ----
        #pragma unroll
        for (int rt = 0; rt < 2; ++rt)
            #pragma unroll
            for (int ct = 0; ct < 4; ++ct)
                #pragma unroll
                for (int rr = 0; rr < 4; ++rr)
                    sH[wave * 32 + rt * 16 + q * 4 + rr][ct * 16 + m] =
                        (bf16)fast_gelu(S[rt][ct][rr]);
        asm volatile("s_waitcnt lgkmcnt(0)" ::: "memory");  // own-wave RAW on sH

        // ---- GEMM2: O += gelu(H) @ W2c ----
        #pragma unroll
        for (int k2 = 0; k2 < 2; ++k2) {
            bf16x8 h0 = *(const bf16x8*)&sH[wave * 32 +  0 + m][k2 * 32 + q * 8];
            bf16x8 h1 = *(const bf16x8*)&sH[wave * 32 + 16 + m][k2 * 32 + q * 8];
            #pragma unroll
            for (int ct = 0; ct < 8; ++ct) {
                bf16x8 b = *(const bf16x8*)&sW2[ct * 16 + m][k2 * 32 + q * 8];
                O[0][ct] = MFMA16(h0, b, O[0][ct]);
                O[1][ct] = MFMA16(h1, b, O[1][ct]);
            }
        }
    }

    // ---- epilogue: out[b, inst, n] fp32 ----
    #pragma unroll
    for (int rt = 0; rt < 2; ++rt)
        #pragma unroll
        for (int ct = 0; ct < 8; ++ct)
            #pragma unroll
            for (int rr = 0; rr < 4; ++rr) {
                const int b = btile * BM + wave * 32 + rt * 16 + q * 4 + rr;
                const int n = ct * 16 + m;
                out[((size_t)b * NI + inst) * NN + n] = O[rt][ct][rr];
            }
}

extern "C" void kernel_launch(void* const* d_in, const int* in_sizes, int n_in,
                              void* d_out, int out_size, void* d_ws, size_t ws_size,
                              hipStream_t stream)
{
    const int*   a    = (const int*)d_in[0];
    const float* embL = (const float*)d_in[1];
    const float* embR = (const float*)d_in[2];
    const float* lin  = (const float*)d_in[3];   // [NI][E][HID] f32
    const float* une  = (const float*)d_in[4];   // [NI][HID][NN] f32
    float* out = (float*)d_out;

    const size_t w1t_elems = (size_t)NI * HID * E;   // 16.78M bf16
    const size_t w2t_elems = (size_t)NI * NN * HID;  //  8.39M bf16
    const size_t need = (w1t_elems + w2t_elems) * sizeof(bf16);  // ~50 MB

    const int nblocks = (BATCH / BM) * NI;  // 1024

    if (ws_size >= need) {
        bf16* w1t = (bf16*)d_ws;
        bf16* w2t = w1t + w1t_elems;
        transpose_cvt<<<dim3(HID / 64, E / 64, NI), 256, 0, stream>>>(
            lin, w1t, E, HID);        // -> [NI][HID][E]
        transpose_cvt<<<dim3(NN / 64, HID / 64, NI), 256, 0, stream>>>(
            une, w2t, HID, NN);       // -> [NI][NN][HID]
        mlp3_fused<true><<<nblocks, 256, 0, stream>>>(
            a, embL, embR, (const void*)w1t, (const void*)w2t, out);
    } else {
        mlp3_fused<false><<<nblocks, 256, 0, stream>>>(
            a, embL, embR, (const void*)lin, (const void*)une, out);
    }
}